// Round 6
// baseline (252.144 us; speedup 1.0000x reference)
//
#include <hip/hip_runtime.h>
#include <hip/hip_bf16.h>
#include <hip/hip_fp8.h>

// Problem constants (fixed shapes: N=M=8192, D=1024)
#define D_K 1024
#define TILE 128
#define ROWB 512     // bytes per fp4 row (1024 elems * 4 bits)
#define KB_ITER 128  // bytes staged per row per K-iter (= 256 elements)

typedef int intx8 __attribute__((ext_vector_type(8)));
typedef float floatx4 __attribute__((ext_vector_type(4)));

// Encode scaled value (target grid = e2m1 {0,.5,1,1.5,2,3,4,6}) -> 4-bit code.
__device__ __forceinline__ unsigned int f2fp4(float v) {
    const float a = fabsf(v);
    unsigned int c = (unsigned int)(a >= 0.25f) + (a >= 0.75f) + (a >= 1.25f)
                   + (a >= 1.75f) + (a >= 2.5f) + (a >= 3.5f) + (a >= 5.0f);
    return c | (v < 0.0f ? 8u : 0u);
}

// async global->LDS, 16B per lane. LDS dest must be wave-uniform base + lane*16
// (holds: our cc = wavebase + lane); global src may be per-lane arbitrary.
__device__ __forceinline__ void gl_lds16(const void* g, void* l) {
    __builtin_amdgcn_global_load_lds(
        (const __attribute__((address_space(1))) unsigned int*)g,
        (__attribute__((address_space(3))) unsigned int*)l,
        16, 0, 0);
}

// Load one 16B fp4 fragment (32 K-elems) from a row whose 16B chunks are
// stored XOR-swizzled: LDS slot s holds global chunk s ^ e (e = row & 7).
// fp4 data occupies v[0:3] of the 8-reg MFMA operand; upper half zero.
// R4 lesson (bank math): row stride = 128 B = 32 banks, so the row index
// contributes NOTHING to banking; conflict-freedom comes ONLY from the
// quad-varying chunk index (c = t*4 + quad) -> 8 slots x 2 lanes = 2-way
// = free. The 32x32 shape (all 32 lanes share one chunk) is 4-way: dead end.
__device__ __forceinline__ intx8 ld_frag4(const unsigned char* rowbase, int c, int e) {
    const int4 d = *(const int4*)(rowbase + ((c ^ e) * 16));
    intx8 v;
    v[0] = d.x; v[1] = d.y; v[2] = d.z; v[3] = d.w;
    v[4] = 0; v[5] = 0; v[6] = 0; v[7] = 0;
    return v;
}

// ---------------------------------------------------------------------------
// Kernel 1: per-row normalize q,n -> fp4 e2m1 (pre-scaled x32, compensated by
// MFMA e8m0 scale 2^-5 per side); positive-pair term per row.
// One WAVE per row (4 rows/block): no barriers, butterfly reduce in-wave.
// Also zeroes the gemm's last-block ticket counter (stream-ordered: prep
// always completes before gemm starts -> graph-replay-safe reset).
// ---------------------------------------------------------------------------
__global__ __launch_bounds__(256)
void prep_kernel(const float* __restrict__ q, const float* __restrict__ p,
                 const float* __restrict__ ng,
                 unsigned short* __restrict__ qn, unsigned short* __restrict__ nn,
                 float* __restrict__ posp, unsigned int* __restrict__ ticket) {
    if (blockIdx.x == 0 && threadIdx.x == 0) *ticket = 0u;

    const int wid = threadIdx.x >> 6, lane = threadIdx.x & 63;
    const int row = blockIdx.x * 4 + wid;
    const size_t base = (size_t)row * D_K;
    const float4* q4 = (const float4*)(q + base);
    const float4* p4 = (const float4*)(p + base);
    const float4* n4 = (const float4*)(ng + base);

    float4 qa[4], na[4];
    float qq = 0.f, pp = 0.f, qp = 0.f, nn2 = 0.f;
#pragma unroll
    for (int j = 0; j < 4; j++) {
        qa[j] = q4[j * 64 + lane];
        float4 pa = p4[j * 64 + lane];
        na[j] = n4[j * 64 + lane];
        qq += qa[j].x*qa[j].x + qa[j].y*qa[j].y + qa[j].z*qa[j].z + qa[j].w*qa[j].w;
        pp += pa.x*pa.x + pa.y*pa.y + pa.z*pa.z + pa.w*pa.w;
        qp += qa[j].x*pa.x + qa[j].y*pa.y + qa[j].z*pa.z + qa[j].w*pa.w;
        nn2 += na[j].x*na[j].x + na[j].y*na[j].y + na[j].z*na[j].z + na[j].w*na[j].w;
    }
#pragma unroll
    for (int off = 1; off < 64; off <<= 1) {
        qq += __shfl_xor(qq, off);
        pp += __shfl_xor(pp, off);
        qp += __shfl_xor(qp, off);
        nn2 += __shfl_xor(nn2, off);
    }
    const float rq = 32.0f / fmaxf(sqrtf(qq), 1e-8f);   // x32 pre-scale folded in
    const float rn = 32.0f / fmaxf(sqrtf(nn2), 1e-8f);

    // row = 512 B = 256 ushorts; ushort j*64+lane packs elems (j*64+lane)*4..+3
    unsigned short* qr = qn + (size_t)row * 256;
    unsigned short* nr = nn + (size_t)row * 256;
#pragma unroll
    for (int j = 0; j < 4; j++) {
        unsigned int w = f2fp4(qa[j].x * rq) | (f2fp4(qa[j].y * rq) << 4)
                       | (f2fp4(qa[j].z * rq) << 8) | (f2fp4(qa[j].w * rq) << 12);
        qr[j * 64 + lane] = (unsigned short)w;
        w = f2fp4(na[j].x * rn) | (f2fp4(na[j].y * rn) << 4)
          | (f2fp4(na[j].z * rn) << 8) | (f2fp4(na[j].w * rn) << 12);
        nr[j * 64 + lane] = (unsigned short)w;
    }

    if (lane == 0) {
        const float rp = 1.0f / fmaxf(sqrtf(pp), 1e-8f);
        const float sim = qp * (rq / 32.0f) * rp;
        const float ap = fmaxf(1.5f - sim, 0.0f);          // clamp_min(-s + (1+m), 0), m=0.5
        const float sp = -ap * (sim - 0.5f);               // -ap*(s - (1-m))
        posp[row] = __expf(sp - 4.0f);                     // shift C=4 (s_pos <= 3.75)
    }
}

// ---------------------------------------------------------------------------
// Kernel 2 (R12): EXACT R0 GEMM body — the proven plateau. Ledger: R0=45.8
// beats 256²-2ph (50.8), 256²-8ph (57.6), 128²-dbuf (54.3), 32x32 (50.0),
// no-LDS (122.8). At NT=4 the schedule is fill/drain-dominated and the
// inter-block overlap (~2.8 blocks/CU) is the latency-hiding mechanism;
// every occupancy- or barrier-structure change regressed monotonically.
// 3.0 PF here vs m153's 2878 TF ladder point: structural ceiling.
// ONLY change vs R0: finalize is fused in via a deterministic last-block
// pattern (threadfence + ticket atomic; fixed-order double reduction ->
// bitwise-stable result regardless of which block runs it). Saves one
// kernel launch + dispatch from the critical path.
// ---------------------------------------------------------------------------
__global__ __launch_bounds__(256, 2)
void gemm_lse_fp4(const unsigned char* __restrict__ A,
                  const unsigned char* __restrict__ B,
                  float* __restrict__ negp,
                  const float* __restrict__ posp, int n_pos,
                  unsigned int* __restrict__ ticket,
                  float* __restrict__ out) {
    __shared__ unsigned char As[TILE * KB_ITER];   // 16 KB
    __shared__ unsigned char Bs[TILE * KB_ITER];   // 16 KB

    const int tid = threadIdx.x;
    const int wid = tid >> 6;
    const int lane = tid & 63;
    const int tile_m = blockIdx.y * TILE;
    const int tile_n = blockIdx.x * TILE;

    const int wave_m = (wid & 1) * 64;
    const int wave_n = (wid >> 1) * 64;
    const int quad = lane >> 4;
    const int r = lane & 15;
    const int e = r & 7;

    floatx4 acc[4][4] = {};

    // staging: 1024 16B-chunks per matrix per iter, 4 per thread each.
    // LDS linear (slot = cc); global source chunk XOR-swizzled.
    int lds_off[4];
    size_t src_off[4];
#pragma unroll
    for (int s = 0; s < 4; s++) {
        const int cc = s * 256 + tid;
        const int row = cc >> 3, slot = cc & 7;
        lds_off[s] = cc * 16;
        src_off[s] = (size_t)row * ROWB + (size_t)((slot ^ (row & 7)) * 16);
    }
    const unsigned char* Ab = A + (size_t)tile_m * ROWB;
    const unsigned char* Bb = B + (size_t)tile_n * ROWB;

    for (int k0b = 0; k0b < ROWB; k0b += KB_ITER) {
#pragma unroll
        for (int s = 0; s < 4; s++) {
            gl_lds16(Ab + src_off[s] + k0b, &As[lds_off[s]]);
            gl_lds16(Bb + src_off[s] + k0b, &Bs[lds_off[s]]);
        }
        __syncthreads();   // drains vmcnt for the DMA + barrier

#pragma unroll
        for (int t = 0; t < 2; t++) {
            intx8 a[4], b[4];
#pragma unroll
            for (int i = 0; i < 4; i++)
                a[i] = ld_frag4(&As[(wave_m + i * 16 + r) * KB_ITER], t * 4 + quad, e);
#pragma unroll
            for (int j = 0; j < 4; j++)
                b[j] = ld_frag4(&Bs[(wave_n + j * 16 + r) * KB_ITER], t * 4 + quad, e);

#pragma unroll
            for (int i = 0; i < 4; i++)
#pragma unroll
                for (int j = 0; j < 4; j++)
                    acc[i][j] = __builtin_amdgcn_mfma_scale_f32_16x16x128_f8f6f4(
                        a[i], b[j], acc[i][j],
                        4, 4,                 // cbsz=4 / blgp=4: A,B fp4 e2m1
                        0, 0x7A7A7A7A,        // scale_a = 122 -> 2^-5
                        0, 0x7A7A7A7A);       // scale_b = 122 -> 2^-5
        }

        __syncthreads();   // protect LDS before next stage
    }

    // epilogue: circle-loss transform + exp-sum (shift C=4; s_neg <= ~4)
    float lsum = 0.0f;
#pragma unroll
    for (int i = 0; i < 4; i++)
#pragma unroll
        for (int j = 0; j < 4; j++)
#pragma unroll
            for (int el = 0; el < 4; el++) {
                const float s = acc[i][j][el];
                const float an = fmaxf(s + 1.5f, 0.0f);    // clamp_min(s + (1+m), 0)
                const float sn = an * (s + 0.5f);          // an*(s - delta_n), delta_n = -(1-m)
                lsum += __expf(sn - 4.0f);
            }
    for (int off = 32; off > 0; off >>= 1) lsum += __shfl_down(lsum, off);
    __shared__ float red[4];
    if (lane == 0) red[wid] = lsum;
    __syncthreads();

    const int n_neg = gridDim.x * gridDim.y;
    __shared__ bool isLast;
    if (tid == 0) {
        negp[blockIdx.y * gridDim.x + blockIdx.x] = red[0] + red[1] + red[2] + red[3];
        __threadfence();                       // release: partial visible device-wide
        const unsigned int t = atomicAdd(ticket, 1u);   // device-scope by default
        isLast = (t == (unsigned int)(n_neg - 1));
    }
    __syncthreads();

    if (isLast) {
        // acquire: all other blocks' release-fences ordered before our atomic
        __threadfence();
        double sn = 0.0, sp = 0.0;
        for (int i = tid; i < n_neg; i += 256) sn += (double)negp[i];
        for (int i = tid; i < n_pos; i += 256) sp += (double)posp[i];
        for (int off = 32; off > 0; off >>= 1) {
            sn += __shfl_down(sn, off);
            sp += __shfl_down(sp, off);
        }
        __shared__ double rn[4], rp[4];
        if (lane == 0) { rn[wid] = sn; rp[wid] = sp; }
        __syncthreads();
        if (tid == 0) {
            const double NS = rn[0] + rn[1] + rn[2] + rn[3];
            const double PS = rp[0] + rp[1] + rp[2] + rp[3];
            const double x = (4.0 + log(NS)) + (4.0 + log(PS));
            const double spl = (x > 30.0) ? x : log1p(exp(x));
            out[0] = (float)spl;
        }
    }
}

extern "C" void kernel_launch(void* const* d_in, const int* in_sizes, int n_in,
                              void* d_out, int out_size, void* d_ws, size_t ws_size,
                              hipStream_t stream) {
    const float* q = (const float*)d_in[0];
    const float* p = (const float*)d_in[1];
    const float* ng = (const float*)d_in[2];
    // d_in[3] (text_neg_index) is unused in this branch of the reference.

    const int N = in_sizes[3];          // 8192
    const int D = in_sizes[0] / N;      // 1024 (== D_K)
    const int M = in_sizes[2] / D;      // 8192

    char* ws = (char*)d_ws;
    unsigned short* qn = (unsigned short*)ws;                       // N*512 B
    unsigned short* nn = (unsigned short*)(ws + (size_t)N * ROWB);  // M*512 B
    float* negp = (float*)(ws + (size_t)(N + M) * ROWB);
    const int n_neg = (M / TILE) * (N / TILE);
    float* posp = negp + n_neg;
    unsigned int* ticket = (unsigned int*)(posp + N);

    // N == M for this problem, so one prep pass covers q/p rows and n rows.
    prep_kernel<<<N / 4, 256, 0, stream>>>(q, p, ng, qn, nn, posp, ticket);
    gemm_lse_fp4<<<dim3(M / TILE, N / TILE), 256, 0, stream>>>(
        (const unsigned char*)qn, (const unsigned char*)nn, negp,
        posp, N, ticket, (float*)d_out);
}

// Round 7
// 169.567 us; speedup vs baseline: 1.4870x; 1.4870x over previous
//
#include <hip/hip_runtime.h>
#include <hip/hip_bf16.h>
#include <hip/hip_fp8.h>

// Problem constants (fixed shapes: N=M=8192, D=1024)
#define D_K 1024
#define TILE 128
#define ROWB 512     // bytes per fp4 row (1024 elems * 4 bits)
#define KB_ITER 128  // bytes staged per row per K-iter (= 256 elements)

typedef int intx8 __attribute__((ext_vector_type(8)));
typedef float floatx4 __attribute__((ext_vector_type(4)));

// Encode scaled value (target grid = e2m1 {0,.5,1,1.5,2,3,4,6}) -> 4-bit code.
__device__ __forceinline__ unsigned int f2fp4(float v) {
    const float a = fabsf(v);
    unsigned int c = (unsigned int)(a >= 0.25f) + (a >= 0.75f) + (a >= 1.25f)
                   + (a >= 1.75f) + (a >= 2.5f) + (a >= 3.5f) + (a >= 5.0f);
    return c | (v < 0.0f ? 8u : 0u);
}

// async global->LDS, 16B per lane. LDS dest must be wave-uniform base + lane*16
// (holds: our cc = wavebase + lane); global src may be per-lane arbitrary.
__device__ __forceinline__ void gl_lds16(const void* g, void* l) {
    __builtin_amdgcn_global_load_lds(
        (const __attribute__((address_space(1))) unsigned int*)g,
        (__attribute__((address_space(3))) unsigned int*)l,
        16, 0, 0);
}

// Load one 16B fp4 fragment (32 K-elems) from a row whose 16B chunks are
// stored XOR-swizzled: LDS slot s holds global chunk s ^ e (e = row & 7).
// fp4 data occupies v[0:3] of the 8-reg MFMA operand; upper half zero.
// R4 lesson (bank math): row stride = 128 B = 32 banks, so the row index
// contributes NOTHING to banking; conflict-freedom comes ONLY from the
// quad-varying chunk index (c = t*4 + quad) -> 8 slots x 2 lanes = 2-way
// = free. The 32x32 shape (all 32 lanes share one chunk) is 4-way: dead end.
__device__ __forceinline__ intx8 ld_frag4(const unsigned char* rowbase, int c, int e) {
    const int4 d = *(const int4*)(rowbase + ((c ^ e) * 16));
    intx8 v;
    v[0] = d.x; v[1] = d.y; v[2] = d.z; v[3] = d.w;
    v[4] = 0; v[5] = 0; v[6] = 0; v[7] = 0;
    return v;
}

// ---------------------------------------------------------------------------
// Kernel 1: per-row normalize q,n -> fp4 e2m1 (pre-scaled x32, compensated by
// MFMA e8m0 scale 2^-5 per side); positive-pair term per row.
// One WAVE per row (4 rows/block): no barriers, butterfly reduce in-wave.
// ---------------------------------------------------------------------------
__global__ __launch_bounds__(256)
void prep_kernel(const float* __restrict__ q, const float* __restrict__ p,
                 const float* __restrict__ ng,
                 unsigned short* __restrict__ qn, unsigned short* __restrict__ nn,
                 float* __restrict__ posp) {
    const int wid = threadIdx.x >> 6, lane = threadIdx.x & 63;
    const int row = blockIdx.x * 4 + wid;
    const size_t base = (size_t)row * D_K;
    const float4* q4 = (const float4*)(q + base);
    const float4* p4 = (const float4*)(p + base);
    const float4* n4 = (const float4*)(ng + base);

    float4 qa[4], na[4];
    float qq = 0.f, pp = 0.f, qp = 0.f, nn2 = 0.f;
#pragma unroll
    for (int j = 0; j < 4; j++) {
        qa[j] = q4[j * 64 + lane];
        float4 pa = p4[j * 64 + lane];
        na[j] = n4[j * 64 + lane];
        qq += qa[j].x*qa[j].x + qa[j].y*qa[j].y + qa[j].z*qa[j].z + qa[j].w*qa[j].w;
        pp += pa.x*pa.x + pa.y*pa.y + pa.z*pa.z + pa.w*pa.w;
        qp += qa[j].x*pa.x + qa[j].y*pa.y + qa[j].z*pa.z + qa[j].w*pa.w;
        nn2 += na[j].x*na[j].x + na[j].y*na[j].y + na[j].z*na[j].z + na[j].w*na[j].w;
    }
#pragma unroll
    for (int off = 1; off < 64; off <<= 1) {
        qq += __shfl_xor(qq, off);
        pp += __shfl_xor(pp, off);
        qp += __shfl_xor(qp, off);
        nn2 += __shfl_xor(nn2, off);
    }
    const float rq = 32.0f / fmaxf(sqrtf(qq), 1e-8f);   // x32 pre-scale folded in
    const float rn = 32.0f / fmaxf(sqrtf(nn2), 1e-8f);

    // row = 512 B = 256 ushorts; ushort j*64+lane packs elems (j*64+lane)*4..+3
    unsigned short* qr = qn + (size_t)row * 256;
    unsigned short* nr = nn + (size_t)row * 256;
#pragma unroll
    for (int j = 0; j < 4; j++) {
        unsigned int w = f2fp4(qa[j].x * rq) | (f2fp4(qa[j].y * rq) << 4)
                       | (f2fp4(qa[j].z * rq) << 8) | (f2fp4(qa[j].w * rq) << 12);
        qr[j * 64 + lane] = (unsigned short)w;
        w = f2fp4(na[j].x * rn) | (f2fp4(na[j].y * rn) << 4)
          | (f2fp4(na[j].z * rn) << 8) | (f2fp4(na[j].w * rn) << 12);
        nr[j * 64 + lane] = (unsigned short)w;
    }

    if (lane == 0) {
        const float rp = 1.0f / fmaxf(sqrtf(pp), 1e-8f);
        const float sim = qp * (rq / 32.0f) * rp;
        const float ap = fmaxf(1.5f - sim, 0.0f);          // clamp_min(-s + (1+m), 0), m=0.5
        const float sp = -ap * (sim - 0.5f);               // -ap*(s - (1-m))
        posp[row] = __expf(sp - 4.0f);                     // shift C=4 (s_pos <= 3.75)
    }
}

// ---------------------------------------------------------------------------
// Kernel 2 (R13): EXACT R0 GEMM hot loop — the proven plateau. Ledger (gemm
// µs): R0 45.8 < 32x32 50.0 < 256²-2ph 50.8 < 128²-dbuf 54.3 < 256²-8ph 57.6
// < no-LDS 122.8 < fused-fence 138.9. Inter-block overlap (~3 blocks/CU) is
// THE latency-hiding mechanism; every variant that reduced it regressed.
// R6 lesson: device-scope threadfence per block = L2 flush = 3x slowdown;
// finalize stays a separate kernel.
// ONLY change vs R0: the 4-float cross-wave reduce array is ALIASED onto the
// As staging buffer (safe: no wave touches staging LDS after the K-loop's
// final __syncthreads). Declared LDS drops 32784 -> 32768 exactly, so the
// block's LDS allocation leaves the 33280 granule bin -> one more resident
// block per CU by LDS arithmetic (163840/32768 = 5).
// ---------------------------------------------------------------------------
__global__ __launch_bounds__(256, 2)
void gemm_lse_fp4(const unsigned char* __restrict__ A,
                  const unsigned char* __restrict__ B,
                  float* __restrict__ negp) {
    __shared__ unsigned char As[TILE * KB_ITER];   // 16 KB
    __shared__ unsigned char Bs[TILE * KB_ITER];   // 16 KB  (total = 32768 exactly)

    const int tid = threadIdx.x;
    const int wid = tid >> 6;
    const int lane = tid & 63;
    const int tile_m = blockIdx.y * TILE;
    const int tile_n = blockIdx.x * TILE;

    const int wave_m = (wid & 1) * 64;
    const int wave_n = (wid >> 1) * 64;
    const int quad = lane >> 4;
    const int r = lane & 15;
    const int e = r & 7;

    floatx4 acc[4][4] = {};

    // staging: 1024 16B-chunks per matrix per iter, 4 per thread each.
    // LDS linear (slot = cc); global source chunk XOR-swizzled.
    int lds_off[4];
    size_t src_off[4];
#pragma unroll
    for (int s = 0; s < 4; s++) {
        const int cc = s * 256 + tid;
        const int row = cc >> 3, slot = cc & 7;
        lds_off[s] = cc * 16;
        src_off[s] = (size_t)row * ROWB + (size_t)((slot ^ (row & 7)) * 16);
    }
    const unsigned char* Ab = A + (size_t)tile_m * ROWB;
    const unsigned char* Bb = B + (size_t)tile_n * ROWB;

    for (int k0b = 0; k0b < ROWB; k0b += KB_ITER) {
#pragma unroll
        for (int s = 0; s < 4; s++) {
            gl_lds16(Ab + src_off[s] + k0b, &As[lds_off[s]]);
            gl_lds16(Bb + src_off[s] + k0b, &Bs[lds_off[s]]);
        }
        __syncthreads();   // drains vmcnt for the DMA + barrier

#pragma unroll
        for (int t = 0; t < 2; t++) {
            intx8 a[4], b[4];
#pragma unroll
            for (int i = 0; i < 4; i++)
                a[i] = ld_frag4(&As[(wave_m + i * 16 + r) * KB_ITER], t * 4 + quad, e);
#pragma unroll
            for (int j = 0; j < 4; j++)
                b[j] = ld_frag4(&Bs[(wave_n + j * 16 + r) * KB_ITER], t * 4 + quad, e);

#pragma unroll
            for (int i = 0; i < 4; i++)
#pragma unroll
                for (int j = 0; j < 4; j++)
                    acc[i][j] = __builtin_amdgcn_mfma_scale_f32_16x16x128_f8f6f4(
                        a[i], b[j], acc[i][j],
                        4, 4,                 // cbsz=4 / blgp=4: A,B fp4 e2m1
                        0, 0x7A7A7A7A,        // scale_a = 122 -> 2^-5
                        0, 0x7A7A7A7A);       // scale_b = 122 -> 2^-5
        }

        __syncthreads();   // protect LDS before next stage
    }

    // epilogue: circle-loss transform + exp-sum (shift C=4; s_neg <= ~4)
    float lsum = 0.0f;
#pragma unroll
    for (int i = 0; i < 4; i++)
#pragma unroll
        for (int j = 0; j < 4; j++)
#pragma unroll
            for (int el = 0; el < 4; el++) {
                const float s = acc[i][j][el];
                const float an = fmaxf(s + 1.5f, 0.0f);    // clamp_min(s + (1+m), 0)
                const float sn = an * (s + 0.5f);          // an*(s - delta_n), delta_n = -(1-m)
                lsum += __expf(sn - 4.0f);
            }
    for (int off = 32; off > 0; off >>= 1) lsum += __shfl_down(lsum, off);
    // reuse staging LDS for the 4-float cross-wave reduce (keeps block LDS
    // at exactly 32768 B). Safe: last loop iteration ended with __syncthreads,
    // and no wave reads As/Bs after it.
    float* red = (float*)As;
    if (lane == 0) red[wid] = lsum;
    __syncthreads();
    if (tid == 0)
        negp[blockIdx.y * gridDim.x + blockIdx.x] = red[0] + red[1] + red[2] + red[3];
}

// ---------------------------------------------------------------------------
// Kernel 3: reduce partials, assemble softplus(lse_neg + lse_pos).
// ---------------------------------------------------------------------------
__global__ __launch_bounds__(1024)
void finalize_kernel(const float* __restrict__ negp, int n_neg,
                     const float* __restrict__ posp, int n_pos,
                     float* __restrict__ out) {
    double sn = 0.0, sp = 0.0;
    for (int i = threadIdx.x; i < n_neg; i += 1024) sn += (double)negp[i];
    for (int i = threadIdx.x; i < n_pos; i += 1024) sp += (double)posp[i];
    for (int off = 32; off > 0; off >>= 1) {
        sn += __shfl_down(sn, off);
        sp += __shfl_down(sp, off);
    }
    __shared__ double rn[16], rp[16];
    const int wid = threadIdx.x >> 6, lane = threadIdx.x & 63;
    if (lane == 0) { rn[wid] = sn; rp[wid] = sp; }
    __syncthreads();
    if (threadIdx.x == 0) {
        double NS = 0.0, PS = 0.0;
#pragma unroll
        for (int w = 0; w < 16; w++) { NS += rn[w]; PS += rp[w]; }
        const double x = (4.0 + log(NS)) + (4.0 + log(PS));
        const double spl = (x > 30.0) ? x : log1p(exp(x));
        out[0] = (float)spl;
    }
}

extern "C" void kernel_launch(void* const* d_in, const int* in_sizes, int n_in,
                              void* d_out, int out_size, void* d_ws, size_t ws_size,
                              hipStream_t stream) {
    const float* q = (const float*)d_in[0];
    const float* p = (const float*)d_in[1];
    const float* ng = (const float*)d_in[2];
    // d_in[3] (text_neg_index) is unused in this branch of the reference.

    const int N = in_sizes[3];          // 8192
    const int D = in_sizes[0] / N;      // 1024 (== D_K)
    const int M = in_sizes[2] / D;      // 8192

    char* ws = (char*)d_ws;
    unsigned short* qn = (unsigned short*)ws;                       // N*512 B
    unsigned short* nn = (unsigned short*)(ws + (size_t)N * ROWB);  // M*512 B
    float* negp = (float*)(ws + (size_t)(N + M) * ROWB);
    const int n_neg = (M / TILE) * (N / TILE);
    float* posp = negp + n_neg;

    // N == M for this problem, so one prep pass covers q/p rows and n rows.
    prep_kernel<<<N / 4, 256, 0, stream>>>(q, p, ng, qn, nn, posp);
    gemm_lse_fp4<<<dim3(M / TILE, N / TILE), 256, 0, stream>>>(
        (const unsigned char*)qn, (const unsigned char*)nn, negp);
    finalize_kernel<<<1, 1024, 0, stream>>>(negp, n_neg, posp, N, (float*)d_out);
}

// Round 8
// 168.311 us; speedup vs baseline: 1.4981x; 1.0075x over previous
//
#include <hip/hip_runtime.h>
#include <hip/hip_bf16.h>
#include <hip/hip_fp8.h>

// Problem constants (fixed shapes: N=M=8192, D=1024)
#define D_K 1024
#define TILE 128
#define ROWB 512     // bytes per fp4 row (1024 elems * 4 bits)
#define KB_ITER 128  // bytes staged per row per K-iter (= 256 elements)

typedef int intx8 __attribute__((ext_vector_type(8)));
typedef float floatx4 __attribute__((ext_vector_type(4)));

// Encode scaled value (target grid = e2m1 {0,.5,1,1.5,2,3,4,6}) -> 4-bit code.
__device__ __forceinline__ unsigned int f2fp4(float v) {
    const float a = fabsf(v);
    unsigned int c = (unsigned int)(a >= 0.25f) + (a >= 0.75f) + (a >= 1.25f)
                   + (a >= 1.75f) + (a >= 2.5f) + (a >= 3.5f) + (a >= 5.0f);
    return c | (v < 0.0f ? 8u : 0u);
}

// async global->LDS, 16B per lane. LDS dest must be wave-uniform base + lane*16
// (holds: our cc = wavebase + lane); global src may be per-lane arbitrary.
__device__ __forceinline__ void gl_lds16(const void* g, void* l) {
    __builtin_amdgcn_global_load_lds(
        (const __attribute__((address_space(1))) unsigned int*)g,
        (__attribute__((address_space(3))) unsigned int*)l,
        16, 0, 0);
}

// Load one 16B fp4 fragment (32 K-elems) from a row whose 16B chunks are
// stored XOR-swizzled: LDS slot s holds global chunk s ^ e (e = row & 7).
// fp4 data occupies v[0:3] of the 8-reg MFMA operand; upper half zero.
// R4 lesson (bank math): row stride = 128 B = 32 banks, so the row index
// contributes NOTHING to banking; conflict-freedom comes ONLY from the
// quad-varying chunk index (c = t*4 + quad) -> 8 slots x 2 lanes = 2-way
// = free. The 32x32 shape (all 32 lanes share one chunk) is 4-way: dead end.
__device__ __forceinline__ intx8 ld_frag4(const unsigned char* rowbase, int c, int e) {
    const int4 d = *(const int4*)(rowbase + ((c ^ e) * 16));
    intx8 v;
    v[0] = d.x; v[1] = d.y; v[2] = d.z; v[3] = d.w;
    v[4] = 0; v[5] = 0; v[6] = 0; v[7] = 0;
    return v;
}

// ---------------------------------------------------------------------------
// Kernel 1: per-row normalize q,n -> fp4 e2m1 (pre-scaled x32, compensated by
// MFMA e8m0 scale 2^-5 per side); positive-pair term per row.
// One WAVE per row (4 rows/block): no barriers, butterfly reduce in-wave.
// ---------------------------------------------------------------------------
__global__ __launch_bounds__(256)
void prep_kernel(const float* __restrict__ q, const float* __restrict__ p,
                 const float* __restrict__ ng,
                 unsigned short* __restrict__ qn, unsigned short* __restrict__ nn,
                 float* __restrict__ posp) {
    const int wid = threadIdx.x >> 6, lane = threadIdx.x & 63;
    const int row = blockIdx.x * 4 + wid;
    const size_t base = (size_t)row * D_K;
    const float4* q4 = (const float4*)(q + base);
    const float4* p4 = (const float4*)(p + base);
    const float4* n4 = (const float4*)(ng + base);

    float4 qa[4], na[4];
    float qq = 0.f, pp = 0.f, qp = 0.f, nn2 = 0.f;
#pragma unroll
    for (int j = 0; j < 4; j++) {
        qa[j] = q4[j * 64 + lane];
        float4 pa = p4[j * 64 + lane];
        na[j] = n4[j * 64 + lane];
        qq += qa[j].x*qa[j].x + qa[j].y*qa[j].y + qa[j].z*qa[j].z + qa[j].w*qa[j].w;
        pp += pa.x*pa.x + pa.y*pa.y + pa.z*pa.z + pa.w*pa.w;
        qp += qa[j].x*pa.x + qa[j].y*pa.y + qa[j].z*pa.z + qa[j].w*pa.w;
        nn2 += na[j].x*na[j].x + na[j].y*na[j].y + na[j].z*na[j].z + na[j].w*na[j].w;
    }
#pragma unroll
    for (int off = 1; off < 64; off <<= 1) {
        qq += __shfl_xor(qq, off);
        pp += __shfl_xor(pp, off);
        qp += __shfl_xor(qp, off);
        nn2 += __shfl_xor(nn2, off);
    }
    const float rq = 32.0f / fmaxf(sqrtf(qq), 1e-8f);   // x32 pre-scale folded in
    const float rn = 32.0f / fmaxf(sqrtf(nn2), 1e-8f);

    // row = 512 B = 256 ushorts; ushort j*64+lane packs elems (j*64+lane)*4..+3
    unsigned short* qr = qn + (size_t)row * 256;
    unsigned short* nr = nn + (size_t)row * 256;
#pragma unroll
    for (int j = 0; j < 4; j++) {
        unsigned int w = f2fp4(qa[j].x * rq) | (f2fp4(qa[j].y * rq) << 4)
                       | (f2fp4(qa[j].z * rq) << 8) | (f2fp4(qa[j].w * rq) << 12);
        qr[j * 64 + lane] = (unsigned short)w;
        w = f2fp4(na[j].x * rn) | (f2fp4(na[j].y * rn) << 4)
          | (f2fp4(na[j].z * rn) << 8) | (f2fp4(na[j].w * rn) << 12);
        nr[j * 64 + lane] = (unsigned short)w;
    }

    if (lane == 0) {
        const float rp = 1.0f / fmaxf(sqrtf(pp), 1e-8f);
        const float sim = qp * (rq / 32.0f) * rp;
        const float ap = fmaxf(1.5f - sim, 0.0f);          // clamp_min(-s + (1+m), 0), m=0.5
        const float sp = -ap * (sim - 0.5f);               // -ap*(s - (1-m))
        posp[row] = __expf(sp - 4.0f);                     // shift C=4 (s_pos <= 3.75)
    }
}

// ---------------------------------------------------------------------------
// Kernel 2 (R14): R13 hot loop (the proven plateau: 45.8 -> 43.3 via exact-32KB
// LDS) + T1 XCD-aware block swizzle. Theory: panel traffic = 4096 blocks x
// 128 KB = 512 MB/dispatch at 43.3 µs = 11.8 TB/s — an L3-tier ceiling
// (R5's no-LDS run sustained 8.7 TB/s from the same tier), because the
// default round-robin dispatch replicates every panel into all 8 XCD L2s.
// Swizzle: each XCD (= w&7 for dispatch-linear w) owns a 16x32 block region;
// first-touch working set 16 A-panels (1 MB) + 32 B-panels (2 MB) = 3 MB
// < 4 MB L2 -> panel re-reads become XCD-local L2 hits (aggregate 34.5 TB/s,
// memory floor ~15 µs). Bijective for the fixed 64x64 grid; identity guard
// otherwise. negp slot keyed by (by,bx) -> reduction order bitwise-unchanged.
// Ledger (gemm µs): 43.3 (R13) < 45.8 (R0) < 50.0 (32x32) < 50.8 (256²-2ph)
// < 54.3 (dbuf) < 57.6 (256²-8ph) < 122.8 (no-LDS) < 138.9 (fused-fence).
// ---------------------------------------------------------------------------
__global__ __launch_bounds__(256, 2)
void gemm_lse_fp4(const unsigned char* __restrict__ A,
                  const unsigned char* __restrict__ B,
                  float* __restrict__ negp) {
    __shared__ unsigned char As[TILE * KB_ITER];   // 16 KB
    __shared__ unsigned char Bs[TILE * KB_ITER];   // 16 KB  (total = 32768 exactly)

    const int tid = threadIdx.x;
    const int wid = tid >> 6;
    const int lane = tid & 63;

    // --- T1 XCD swizzle: dispatch-linear id w -> (bx, by) region mapping ---
    int bx, by;
    if (gridDim.x == 64 && gridDim.y == 64) {
        const int w = blockIdx.y * 64 + blockIdx.x;   // dispatch order
        const int xcd = w & 7;                        // HW round-robin target
        const int idx = w >> 3;                       // 0..511 within region
        by = ((xcd >> 1) << 4) + (idx >> 5);          // region-row*16 + row
        bx = ((xcd & 1) << 5) + (idx & 31);           // region-col*32 + col
    } else {
        bx = blockIdx.x; by = blockIdx.y;
    }
    const int tile_m = by * TILE;
    const int tile_n = bx * TILE;

    const int wave_m = (wid & 1) * 64;
    const int wave_n = (wid >> 1) * 64;
    const int quad = lane >> 4;
    const int r = lane & 15;
    const int e = r & 7;

    floatx4 acc[4][4] = {};

    // staging: 1024 16B-chunks per matrix per iter, 4 per thread each.
    // LDS linear (slot = cc); global source chunk XOR-swizzled.
    int lds_off[4];
    size_t src_off[4];
#pragma unroll
    for (int s = 0; s < 4; s++) {
        const int cc = s * 256 + tid;
        const int row = cc >> 3, slot = cc & 7;
        lds_off[s] = cc * 16;
        src_off[s] = (size_t)row * ROWB + (size_t)((slot ^ (row & 7)) * 16);
    }
    const unsigned char* Ab = A + (size_t)tile_m * ROWB;
    const unsigned char* Bb = B + (size_t)tile_n * ROWB;

    for (int k0b = 0; k0b < ROWB; k0b += KB_ITER) {
#pragma unroll
        for (int s = 0; s < 4; s++) {
            gl_lds16(Ab + src_off[s] + k0b, &As[lds_off[s]]);
            gl_lds16(Bb + src_off[s] + k0b, &Bs[lds_off[s]]);
        }
        __syncthreads();   // drains vmcnt for the DMA + barrier

#pragma unroll
        for (int t = 0; t < 2; t++) {
            intx8 a[4], b[4];
#pragma unroll
            for (int i = 0; i < 4; i++)
                a[i] = ld_frag4(&As[(wave_m + i * 16 + r) * KB_ITER], t * 4 + quad, e);
#pragma unroll
            for (int j = 0; j < 4; j++)
                b[j] = ld_frag4(&Bs[(wave_n + j * 16 + r) * KB_ITER], t * 4 + quad, e);

#pragma unroll
            for (int i = 0; i < 4; i++)
#pragma unroll
                for (int j = 0; j < 4; j++)
                    acc[i][j] = __builtin_amdgcn_mfma_scale_f32_16x16x128_f8f6f4(
                        a[i], b[j], acc[i][j],
                        4, 4,                 // cbsz=4 / blgp=4: A,B fp4 e2m1
                        0, 0x7A7A7A7A,        // scale_a = 122 -> 2^-5
                        0, 0x7A7A7A7A);       // scale_b = 122 -> 2^-5
        }

        __syncthreads();   // protect LDS before next stage
    }

    // epilogue: circle-loss transform + exp-sum (shift C=4; s_neg <= ~4)
    float lsum = 0.0f;
#pragma unroll
    for (int i = 0; i < 4; i++)
#pragma unroll
        for (int j = 0; j < 4; j++)
#pragma unroll
            for (int el = 0; el < 4; el++) {
                const float s = acc[i][j][el];
                const float an = fmaxf(s + 1.5f, 0.0f);    // clamp_min(s + (1+m), 0)
                const float sn = an * (s + 0.5f);          // an*(s - delta_n), delta_n = -(1-m)
                lsum += __expf(sn - 4.0f);
            }
    for (int off = 32; off > 0; off >>= 1) lsum += __shfl_down(lsum, off);
    // reuse staging LDS for the 4-float cross-wave reduce (keeps block LDS
    // at exactly 32768 B). Safe: last loop iteration ended with __syncthreads,
    // and no wave reads As/Bs after it.
    float* red = (float*)As;
    if (lane == 0) red[wid] = lsum;
    __syncthreads();
    if (tid == 0)
        negp[by * gridDim.x + bx] = red[0] + red[1] + red[2] + red[3];
}

// ---------------------------------------------------------------------------
// Kernel 3: reduce partials, assemble softplus(lse_neg + lse_pos).
// ---------------------------------------------------------------------------
__global__ __launch_bounds__(1024)
void finalize_kernel(const float* __restrict__ negp, int n_neg,
                     const float* __restrict__ posp, int n_pos,
                     float* __restrict__ out) {
    double sn = 0.0, sp = 0.0;
    for (int i = threadIdx.x; i < n_neg; i += 1024) sn += (double)negp[i];
    for (int i = threadIdx.x; i < n_pos; i += 1024) sp += (double)posp[i];
    for (int off = 32; off > 0; off >>= 1) {
        sn += __shfl_down(sn, off);
        sp += __shfl_down(sp, off);
    }
    __shared__ double rn[16], rp[16];
    const int wid = threadIdx.x >> 6, lane = threadIdx.x & 63;
    if (lane == 0) { rn[wid] = sn; rp[wid] = sp; }
    __syncthreads();
    if (threadIdx.x == 0) {
        double NS = 0.0, PS = 0.0;
#pragma unroll
        for (int w = 0; w < 16; w++) { NS += rn[w]; PS += rp[w]; }
        const double x = (4.0 + log(NS)) + (4.0 + log(PS));
        const double spl = (x > 30.0) ? x : log1p(exp(x));
        out[0] = (float)spl;
    }
}

extern "C" void kernel_launch(void* const* d_in, const int* in_sizes, int n_in,
                              void* d_out, int out_size, void* d_ws, size_t ws_size,
                              hipStream_t stream) {
    const float* q = (const float*)d_in[0];
    const float* p = (const float*)d_in[1];
    const float* ng = (const float*)d_in[2];
    // d_in[3] (text_neg_index) is unused in this branch of the reference.

    const int N = in_sizes[3];          // 8192
    const int D = in_sizes[0] / N;      // 1024 (== D_K)
    const int M = in_sizes[2] / D;      // 8192

    char* ws = (char*)d_ws;
    unsigned short* qn = (unsigned short*)ws;                       // N*512 B
    unsigned short* nn = (unsigned short*)(ws + (size_t)N * ROWB);  // M*512 B
    float* negp = (float*)(ws + (size_t)(N + M) * ROWB);
    const int n_neg = (M / TILE) * (N / TILE);
    float* posp = negp + n_neg;

    // N == M for this problem, so one prep pass covers q/p rows and n rows.
    prep_kernel<<<N / 4, 256, 0, stream>>>(q, p, ng, qn, nn, posp);
    gemm_lse_fp4<<<dim3(M / TILE, N / TILE), 256, 0, stream>>>(
        (const unsigned char*)qn, (const unsigned char*)nn, negp);
    finalize_kernel<<<1, 1024, 0, stream>>>(negp, n_neg, posp, N, (float*)d_out);
}